// Round 7
// baseline (61.778 us; speedup 1.0000x reference)
//
#include <hip/hip_runtime.h>
#include <stdint.h>
#include <math.h>

#define NLVL 16
#define NPTS 131072
#define BPTS 64            // points per block (part 1)
#define NTHR 256           // 4 waves

// d_ws layout
#define OFF_COUNT 0        // uint
#define OFF_CV    64       // float[32] corner values (16 levels x 2)
#define OFF_FLAG  256      // uint[NPTS/32] corner bitmask (16 KB)
#define OFF_LIST  16640    // int[NPTS] compacted non-corner indices (512 KB)
#define WS_NEED   (16640 + NPTS * 4)

#define GRID_P1   (NPTS / BPTS)          // 2048
#define GRID_P2   (NPTS * 8 / 1024)      // 1024 (1M float4 / 1024 per block)

struct Meta {
  int scales[NLVL];
  int offsets[NLVL];
  unsigned int T;
  int start_hash;
  double invT;
};

// h < 2^38, T ~ 2^19. (double)h exact; q off by at most +-1, fixed up.
__device__ __forceinline__ int fastmod(uint64_t h, unsigned int T, double invT) {
  uint64_t q = (uint64_t)((double)h * invT);
  long long r = (long long)(h - q * (uint64_t)T);
  if (r < 0) r += (long long)T;
  else if (r >= (long long)T) r -= (long long)T;
  return (int)r;
}

// 8 corner indices (level offset folded in) + fractional offsets for level l.
// Bit-matches fp32 reference: corner index = (int)(fx + corner_f32).
__device__ __forceinline__ void level_idx(
    int l, float xn, float yn, float zn, const Meta& m,
    int* __restrict__ idx, float* __restrict__ o)
{
#pragma clang fp contract(off)
  const float sf = (float)m.scales[l];
  const float fx = xn * sf, fy = yn * sf, fz = zn * sf;
  const int ix0 = (int)fx,          iy0 = (int)fy,          iz0 = (int)fz;
  const int ix1 = (int)(fx + 1.0f), iy1 = (int)(fy + 1.0f), iz1 = (int)(fz + 1.0f);
  o[0] = fx - (float)ix0; o[1] = fy - (float)iy0; o[2] = fz - (float)iz0;
  const int base = m.offsets[l];

  if (l < m.start_hash) {
    const int sp1 = m.scales[l] + 1;
    const int sq  = sp1 * sp1;
    const int ax0 = ix0 * sq,  ax1 = ix1 * sq;
    const int ay0 = iy0 * sp1, ay1 = iy1 * sp1;
    idx[0] = base + ax0 + ay0 + iz0;
    idx[1] = base + ax0 + ay0 + iz1;
    idx[2] = base + ax0 + ay1 + iz0;
    idx[3] = base + ax0 + ay1 + iz1;
    idx[4] = base + ax1 + ay0 + iz0;
    idx[5] = base + ax1 + ay0 + iz1;
    idx[6] = base + ax1 + ay1 + iz0;
    idx[7] = base + ax1 + ay1 + iz1;
  } else {
    const uint64_t hx0 = (uint64_t)ix0;
    const uint64_t hx1 = (uint64_t)ix1;
    const uint64_t hy0 = (uint64_t)iy0 * 19349663ull;
    const uint64_t hy1 = hy0 + 19349663ull;
    const uint64_t hz0 = (uint64_t)iz0 * 83492791ull;
    const uint64_t hz1 = hz0 + 83492791ull;
    idx[0] = base + fastmod(hx0 ^ hy0 ^ hz0, m.T, m.invT);
    idx[1] = base + fastmod(hx0 ^ hy0 ^ hz1, m.T, m.invT);
    idx[2] = base + fastmod(hx0 ^ hy1 ^ hz0, m.T, m.invT);
    idx[3] = base + fastmod(hx0 ^ hy1 ^ hz1, m.T, m.invT);
    idx[4] = base + fastmod(hx1 ^ hy0 ^ hz0, m.T, m.invT);
    idx[5] = base + fastmod(hx1 ^ hy0 ^ hz1, m.T, m.invT);
    idx[6] = base + fastmod(hx1 ^ hy1 ^ hz0, m.T, m.invT);
    idx[7] = base + fastmod(hx1 ^ hy1 ^ hz1, m.T, m.invT);
  }
}

// ---------------- Kernel A: classify + compact + corner precompute ----------
__global__ __launch_bounds__(NTHR) void hg_classify(
    const float* __restrict__ xyz,
    const float* __restrict__ wb,
    const float* __restrict__ data,
    unsigned int* __restrict__ count,
    float* __restrict__ cornerval,
    unsigned int* __restrict__ flagw,
    int* __restrict__ list,
    Meta meta)
{
#pragma clang fp contract(off)
  const int t    = threadIdx.x;
  const int lane = t & 63;
  const int p    = blockIdx.x * NTHR + t;

  const float bx0 = wb[0], by0 = wb[1], bz0 = wb[2];
  const float bx1 = wb[3], by1 = wb[4], bz1 = wb[5];

  const float x = xyz[3 * p + 0], y = xyz[3 * p + 1], z = xyz[3 * p + 2];
  const float cx = fminf(fmaxf(x, bx0), bx1);
  const float cy = fminf(fmaxf(y, by0), by1);
  const float cz = fminf(fmaxf(z, bz0), bz1);
  const bool corner = (cx == bx0) && (cy == by0) && (cz == bz0);

  const unsigned long long mc = __ballot(corner);
  const unsigned long long mn = __ballot(!corner);

  // Corner bitmask: each wave exclusively owns 2 words.
  const int pw = blockIdx.x * NTHR + (t & ~63);
  if (lane == 0)  flagw[(pw >> 5) + 0] = (unsigned int)(mc & 0xffffffffull);
  if (lane == 32) flagw[(pw >> 5) + 1] = (unsigned int)(mc >> 32);

  // Wave-aggregated compaction of non-corner indices.
  unsigned int base = 0;
  if (lane == 0) base = atomicAdd(count, (unsigned int)__popcll(mn));
  base = (unsigned int)__shfl((int)base, 0, 64);
  if (!corner) {
    const unsigned int pos =
        base + (unsigned int)__popcll(mn & ((1ull << lane) - 1ull));
    list[pos] = p;
  }

  // Corner-point result: block 0, lanes 0..15 compute one level each with
  // xn = yn = zn = 0 (identical FP path to the per-point computation).
  if (blockIdx.x == 0 && t < 16) {
    int idx[8];
    float o[3];
    level_idx(t, 0.0f, 0.0f, 0.0f, meta, idx, o);
    const float2* __restrict__ dp = (const float2*)data;
    float2 v[8];
#pragma unroll
    for (int k = 0; k < 8; ++k) v[k] = dp[idx[k]];
    const float wx[2] = {1.0f - o[0], o[0]};
    const float wy[2] = {1.0f - o[1], o[1]};
    const float wz[2] = {1.0f - o[2], o[2]};
    float a0 = 0.0f, a1 = 0.0f;
#pragma unroll
    for (int c = 0; c < 8; ++c) {
      const float w = (wx[(c >> 2) & 1] * wy[(c >> 1) & 1]) * wz[c & 1];
      a0 += w * v[c].x;
      a1 += w * v[c].y;
    }
    reinterpret_cast<float2*>(cornerval)[t] = make_float2(a0, a1);
  }
}

// ---------------- Kernel B: main gather (compacted) + corner broadcast ------
__global__ __launch_bounds__(NTHR) void hg_main(
    const float* __restrict__ xyz,
    const float* __restrict__ wb,
    const float* __restrict__ data,
    float* __restrict__ out,
    const unsigned int* __restrict__ count,
    const float* __restrict__ cornerval,
    const unsigned int* __restrict__ flagw,
    const int* __restrict__ list,
    Meta meta)
{
#pragma clang fp contract(off)
  const int t = threadIdx.x;

  if (blockIdx.x >= GRID_P1) {
    // ---- Part 2: broadcast corner result to all flagged points ----
    const int b2 = blockIdx.x - GRID_P1;
    const float4 cv = reinterpret_cast<const float4*>(cornerval)[t & 7];
    float4* __restrict__ out4 = reinterpret_cast<float4*>(out);
#pragma unroll
    for (int it = 0; it < 4; ++it) {
      const int fi = b2 * 1024 + it * NTHR + t;   // float4 index
      const int p  = fi >> 3;
      const unsigned int w = flagw[p >> 5];
      if ((w >> (p & 31)) & 1u) out4[fi] = cv;
    }
    return;
  }

  // ---- Part 1: R4 structure over compacted non-corner points ----
  const int cntNC = (int)*count;
  const int pbase = blockIdx.x * BPTS;
  if (pbase >= cntNC) return;

  const int wave = t >> 6;
  const int lane = t & 63;

  __shared__ int    spid[BPTS];
  __shared__ float  sxyz[BPTS * 3];
  __shared__ int    hist[64];
  __shared__ int    sidx[BPTS];
  __shared__ float2 tile[BPTS][NLVL + 1];

  if (t < 64) {
    const int li  = pbase + t;
    const int pid = (li < cntNC) ? list[li] : -1;
    spid[t] = pid;
    const int sp = pid < 0 ? 0 : pid;
    sxyz[t * 3 + 0] = xyz[sp * 3 + 0];
    sxyz[t * 3 + 1] = xyz[sp * 3 + 1];
    sxyz[t * 3 + 2] = xyz[sp * 3 + 2];
    hist[t] = 0;
  }
  __syncthreads();

  const float bx0 = wb[0], by0 = wb[1], bz0 = wb[2];
  const float bx1 = wb[3], by1 = wb[4], bz1 = wb[5];
  const float denom = fmaxf(fmaxf(bx1 - bx0, by1 - by0), bz1 - bz0) + 1e-6f;

  // Spatial key + histogram (slots 0..63)
  int key = 0;
  if (t < 64) {
    float px = sxyz[t * 3 + 0], py = sxyz[t * 3 + 1], pz = sxyz[t * 3 + 2];
    px = fminf(fmaxf(px, bx0), bx1);
    py = fminf(fmaxf(py, by0), by1);
    pz = fminf(fmaxf(pz, bz0), bz1);
    const float xn = (px - bx0) / denom;
    const float yn = (py - by0) / denom;
    const float zn = (pz - bz0) / denom;
    const int kx = min((int)(xn * 4.0f), 3);
    const int ky = min((int)(yn * 4.0f), 3);
    const int kz = min((int)(zn * 4.0f), 3);
    key = kx * 16 + ky * 4 + kz;
    atomicAdd(&hist[key], 1);
  }
  __syncthreads();

  if (t < 64) {
    int v = hist[t];
#pragma unroll
    for (int d = 1; d < 64; d <<= 1) {
      int u = __shfl_up(v, d, 64);
      if (lane >= d) v += u;
    }
    hist[t] = v;
  }
  __syncthreads();

  if (t < 64) {
    const int pos = atomicSub(&hist[key], 1) - 1;
    sidx[pos] = t;
  }
  __syncthreads();

  // Compute: lane processes sorted slot
  const int slot = sidx[lane];
  float px = sxyz[slot * 3 + 0], py = sxyz[slot * 3 + 1], pz = sxyz[slot * 3 + 2];
  px = fminf(fmaxf(px, bx0), bx1);
  py = fminf(fmaxf(py, by0), by1);
  pz = fminf(fmaxf(pz, bz0), bz1);
  const float xn = (px - bx0) / denom;
  const float yn = (py - by0) / denom;
  const float zn = (pz - bz0) / denom;

  const float2* __restrict__ dp = (const float2*)data;

#pragma unroll 2
  for (int s = 0; s < 4; ++s) {
    const int l = wave + 4 * s;
    int idx[8];
    float o[3];
    level_idx(l, xn, yn, zn, meta, idx, o);

    float2 v[8];
#pragma unroll
    for (int k = 0; k < 8; ++k) v[k] = dp[idx[k]];

    const float wx[2] = {1.0f - o[0], o[0]};
    const float wy[2] = {1.0f - o[1], o[1]};
    const float wz[2] = {1.0f - o[2], o[2]};
    float a0 = 0.0f, a1 = 0.0f;
#pragma unroll
    for (int c = 0; c < 8; ++c) {
      const float w = (wx[(c >> 2) & 1] * wy[(c >> 1) & 1]) * wz[c & 1];
      a0 += w * v[c].x;
      a1 += w * v[c].y;
    }
    tile[slot][l] = make_float2(a0, a1);
  }
  __syncthreads();

  // Store (128 B contiguous per point, guarded by validity)
#pragma unroll
  for (int it = 0; it < 2; ++it) {
    const int idx2 = t + it * NTHR;
    const int pp = idx2 >> 3;
    const int q  = idx2 & 7;
    const int pid = spid[pp];
    if (pid >= 0) {
      const float2 e0 = tile[pp][2 * q];
      const float2 e1 = tile[pp][2 * q + 1];
      reinterpret_cast<float4*>(out)[pid * 8 + q] =
          make_float4(e0.x, e0.y, e1.x, e1.y);
    }
  }
}

// ---------------- Fallback: R4 single kernel (if ws too small) --------------
__global__ __launch_bounds__(NTHR) void hashgrid_fwd(
    const float* __restrict__ xyz,
    const float* __restrict__ wb,
    const float* __restrict__ data,
    float* __restrict__ out,
    Meta meta)
{
#pragma clang fp contract(off)
  const int t    = threadIdx.x;
  const int wave = t >> 6;
  const int lane = t & 63;
  const int pbase = blockIdx.x * BPTS;

  __shared__ float  sxyz[BPTS * 3];
  __shared__ int    hist[64];
  __shared__ int    sidx[BPTS];
  __shared__ float2 tile[BPTS][NLVL + 1];

  if (t < 48)
    reinterpret_cast<float4*>(sxyz)[t] =
        reinterpret_cast<const float4*>(xyz + pbase * 3)[t];
  if (t < 64) hist[t] = 0;
  __syncthreads();

  const float bx0 = wb[0], by0 = wb[1], bz0 = wb[2];
  const float bx1 = wb[3], by1 = wb[4], bz1 = wb[5];
  const float denom = fmaxf(fmaxf(bx1 - bx0, by1 - by0), bz1 - bz0) + 1e-6f;

  int key = 0;
  if (t < 64) {
    float px = sxyz[t * 3 + 0], py = sxyz[t * 3 + 1], pz = sxyz[t * 3 + 2];
    px = fminf(fmaxf(px, bx0), bx1);
    py = fminf(fmaxf(py, by0), by1);
    pz = fminf(fmaxf(pz, bz0), bz1);
    const float xn = (px - bx0) / denom;
    const float yn = (py - by0) / denom;
    const float zn = (pz - bz0) / denom;
    const int kx = min((int)(xn * 4.0f), 3);
    const int ky = min((int)(yn * 4.0f), 3);
    const int kz = min((int)(zn * 4.0f), 3);
    key = kx * 16 + ky * 4 + kz;
    atomicAdd(&hist[key], 1);
  }
  __syncthreads();
  if (t < 64) {
    int v = hist[t];
#pragma unroll
    for (int d = 1; d < 64; d <<= 1) {
      int u = __shfl_up(v, d, 64);
      if (lane >= d) v += u;
    }
    hist[t] = v;
  }
  __syncthreads();
  if (t < 64) {
    const int pos = atomicSub(&hist[key], 1) - 1;
    sidx[pos] = t;
  }
  __syncthreads();

  const int p = sidx[lane];
  float px = sxyz[p * 3 + 0], py = sxyz[p * 3 + 1], pz = sxyz[p * 3 + 2];
  px = fminf(fmaxf(px, bx0), bx1);
  py = fminf(fmaxf(py, by0), by1);
  pz = fminf(fmaxf(pz, bz0), bz1);
  const float xn = (px - bx0) / denom;
  const float yn = (py - by0) / denom;
  const float zn = (pz - bz0) / denom;

  const float2* __restrict__ dp = (const float2*)data;

#pragma unroll 2
  for (int s = 0; s < 4; ++s) {
    const int l = wave + 4 * s;
    int idx[8];
    float o[3];
    level_idx(l, xn, yn, zn, meta, idx, o);
    float2 v[8];
#pragma unroll
    for (int k = 0; k < 8; ++k) v[k] = dp[idx[k]];
    const float wx[2] = {1.0f - o[0], o[0]};
    const float wy[2] = {1.0f - o[1], o[1]};
    const float wz[2] = {1.0f - o[2], o[2]};
    float a0 = 0.0f, a1 = 0.0f;
#pragma unroll
    for (int c = 0; c < 8; ++c) {
      const float w = (wx[(c >> 2) & 1] * wy[(c >> 1) & 1]) * wz[c & 1];
      a0 += w * v[c].x;
      a1 += w * v[c].y;
    }
    tile[p][l] = make_float2(a0, a1);
  }
  __syncthreads();

#pragma unroll
  for (int it = 0; it < 2; ++it) {
    const int idx2 = t + it * NTHR;
    const int pp = idx2 >> 3;
    const int q  = idx2 & 7;
    const float2 e0 = tile[pp][2 * q];
    const float2 e1 = tile[pp][2 * q + 1];
    reinterpret_cast<float4*>(out)[(pbase + pp) * 8 + q] =
        make_float4(e0.x, e0.y, e1.x, e1.y);
  }
}

static bool isprime_ll(long long v) {
  if (v < 2) return false;
  for (long long i = 2; i * i <= v; ++i)
    if (v % i == 0) return false;
  return true;
}

extern "C" void kernel_launch(void* const* d_in, const int* in_sizes, int n_in,
                              void* d_out, int out_size, void* d_ws, size_t ws_size,
                              hipStream_t stream) {
  (void)in_sizes; (void)n_in; (void)out_size;

  Meta m;
  long long T = 1LL << 19;
  while (!isprime_ll(T)) ++T;
  const double b = pow(2048.0 / 16.0, 1.0 / 15.0);
  long long off = 0;
  int sh = -1;
  for (int i = 0; i < NLVL; ++i) {
    const int res = (int)(16.0 * pow(b, (double)i));   // matches int(16 * b**i)
    m.scales[i] = res;
    m.offsets[i] = (int)off;
    long long nn = (long long)(res + 1) * (res + 1) * (res + 1);
    if (nn > T) { if (sh < 0) sh = i; nn = T; }
    off += nn;
  }
  m.T = (unsigned int)T;
  m.start_hash = (sh < 0) ? NLVL : sh;
  m.invT = 1.0 / (double)T;

  const float* xyz  = (const float*)d_in[0];
  const float* wbp  = (const float*)d_in[1];
  const float* data = (const float*)d_in[2];
  float* out = (float*)d_out;

  if (ws_size < (size_t)WS_NEED) {
    hipLaunchKernelGGL(hashgrid_fwd, dim3(NPTS / BPTS), dim3(NTHR), 0, stream,
                       xyz, wbp, data, out, m);
    return;
  }

  char* ws = (char*)d_ws;
  unsigned int* count = (unsigned int*)(ws + OFF_COUNT);
  float*        cv    = (float*)(ws + OFF_CV);
  unsigned int* flagw = (unsigned int*)(ws + OFF_FLAG);
  int*          list  = (int*)(ws + OFF_LIST);

  hipMemsetAsync(count, 0, sizeof(unsigned int), stream);
  hipLaunchKernelGGL(hg_classify, dim3(NPTS / NTHR), dim3(NTHR), 0, stream,
                     xyz, wbp, data, count, cv, flagw, list, m);
  hipLaunchKernelGGL(hg_main, dim3(GRID_P1 + GRID_P2), dim3(NTHR), 0, stream,
                     xyz, wbp, data, out, count, cv, flagw, list, m);
}